// Round 2
// baseline (488.598 us; speedup 1.0000x reference)
//
#include <hip/hip_runtime.h>
#include <cstddef>
#include <cstdint>

#define BB 4
#define LL 2048
#define DD 1024
#define HH 16
#define DHD 64
#define QSCALE 0.18033688f  // 0.125 * log2(e): softmax in base-2 domain

typedef short s16x8 __attribute__((ext_vector_type(8)));
typedef short s16x4 __attribute__((ext_vector_type(4)));
typedef float f32x4 __attribute__((ext_vector_type(4)));
typedef unsigned int u32;
typedef u32 u32x2 __attribute__((ext_vector_type(2)));

__device__ __forceinline__ short f2bf(float f) {
  union { float f; u32 u; } x; x.f = f;
  u32 r = x.u + 0x7FFFu + ((x.u >> 16) & 1u);
  return (short)(r >> 16);
}
// pack two f32 -> two bf16 (round-half-up) in one v_perm
__device__ __forceinline__ u32 pack2bf(float a, float b) {
  union { float f; u32 u; } x, y; x.f = a; y.f = b;
  return __builtin_amdgcn_perm(y.u + 0x8000u, x.u + 0x8000u, 0x07060302u);
}
__device__ __forceinline__ void gl2lds16(const short* g, short* l) {
  __builtin_amdgcn_global_load_lds(
      (const __attribute__((address_space(1))) unsigned int*)g,
      (__attribute__((address_space(3))) unsigned int*)l, 16, 0, 0);
}

// ---------------- merged prep: casts + mask (one launch instead of three) ----
// blocks [0,24576): cast q/k/v   (3 x 8192 blocks)
// blocks [24576,28672): cast Wq/Wk/Wv/Wo (4 x 1024 blocks)
// blocks [28672,28680): mask -> additive bias (8 blocks)
__global__ __launch_bounds__(256) void prep_kernel(const float* __restrict__ q,
                                                   const float* __restrict__ k,
                                                   const float* __restrict__ v,
                                                   const float* __restrict__ Wq,
                                                   const float* __restrict__ Wk,
                                                   const float* __restrict__ Wv,
                                                   const float* __restrict__ Wo,
                                                   const int* __restrict__ mask,
                                                   short* __restrict__ qb,
                                                   short* __restrict__ kb,
                                                   short* __restrict__ vb,
                                                   short* __restrict__ Wqb,
                                                   short* __restrict__ Wkb,
                                                   short* __restrict__ Wvb,
                                                   short* __restrict__ Wob,
                                                   float* __restrict__ maskadd) {
  const int bb = blockIdx.x;
  if (bb < 24576) {
    const float* s; short* d;
    const int y = bb >> 13;
    if (y == 0) { s = q; d = qb; }
    else if (y == 1) { s = k; d = kb; }
    else { s = v; d = vb; }
    int i = (bb & 8191) * 256 + threadIdx.x;
    float4 x = ((const float4*)s)[i];
    s16x4 o; o.x = f2bf(x.x); o.y = f2bf(x.y); o.z = f2bf(x.z); o.w = f2bf(x.w);
    ((s16x4*)d)[i] = o;
  } else if (bb < 28672) {
    const int y = (bb - 24576) >> 10;
    const float* s; short* d; float sc = 1.0f;
    if (y == 0) { s = Wq; d = Wqb; sc = QSCALE; }
    else if (y == 1) { s = Wk; d = Wkb; }
    else if (y == 2) { s = Wv; d = Wvb; }
    else { s = Wo; d = Wob; }
    int i = ((bb - 24576) & 1023) * 256 + threadIdx.x;
    float4 x = ((const float4*)s)[i];
    s16x4 o; o.x = f2bf(x.x * sc); o.y = f2bf(x.y * sc); o.z = f2bf(x.z * sc); o.w = f2bf(x.w * sc);
    ((s16x4*)d)[i] = o;
  } else {
    int i = (bb - 28672) * 256 + threadIdx.x;
    int4 m = ((const int4*)mask)[i];
    f32x4 o;
    o[0] = (m.x == 1) ? 0.0f : -30000.0f;
    o[1] = (m.y == 1) ? 0.0f : -30000.0f;
    o[2] = (m.z == 1) ? 0.0f : -30000.0f;
    o[3] = (m.w == 1) ? 0.0f : -30000.0f;
    ((f32x4*)maskadd)[i] = o;
  }
}

// ---------------- shared GEMM core (128x128 tile, bt layout) ----------------
__device__ __forceinline__ void gemm_core(const short* __restrict__ A, const short* __restrict__ B,
                                          int K, int bm, int bn, short* As, short* Bs,
                                          f32x4 (&acc)[4][4]) {
  const int tid = threadIdx.x;
  const int lane = tid & 63, wave = tid >> 6;
  const int wv = __builtin_amdgcn_readfirstlane(wave);
  const int quad = lane >> 4, l16 = lane & 15;
  const int wm = (wave >> 1) * 64, wn = (wave & 1) * 64;
  const short* ap[4]; const short* bp[4]; short* la[4]; short* lb[4];
#pragma unroll
  for (int t = 0; t < 4; ++t) {
    int s = wv * 256 + t * 64 + lane;
    int r = s >> 3, gl = (s & 7) ^ (r & 7);
    ap[t] = A + (size_t)(bm + r) * K + gl * 8;
    bp[t] = B + (size_t)(bn + r) * K + gl * 8;
    la[t] = &As[(wv * 256 + t * 64) * 8];
    lb[t] = &Bs[(wv * 256 + t * 64) * 8];
  }
  const int sw0 = (quad ^ (l16 & 7)) * 8;
  const int sw1 = ((4 + quad) ^ (l16 & 7)) * 8;
  for (int kk = 0; kk < K; kk += 64) {
    __syncthreads();
#pragma unroll
    for (int t = 0; t < 4; ++t) gl2lds16(ap[t] + kk, la[t]);
#pragma unroll
    for (int t = 0; t < 4; ++t) gl2lds16(bp[t] + kk, lb[t]);
    __syncthreads();
#pragma unroll
    for (int c = 0; c < 2; ++c) {
      const int sw = c ? sw1 : sw0;
      s16x8 af[4], bf[4];
#pragma unroll
      for (int t = 0; t < 4; ++t) af[t] = *(const s16x8*)&As[(wm + t * 16 + l16) * 64 + sw];
#pragma unroll
      for (int t = 0; t < 4; ++t) bf[t] = *(const s16x8*)&Bs[(wn + t * 16 + l16) * 64 + sw];
      __builtin_amdgcn_s_setprio(1);
#pragma unroll
      for (int mt = 0; mt < 4; ++mt)
#pragma unroll
        for (int nt = 0; nt < 4; ++nt)
          acc[mt][nt] = __builtin_amdgcn_mfma_f32_16x16x32_bf16(af[mt], bf[nt], acc[mt][nt], 0, 0, 0);
      __builtin_amdgcn_s_setprio(0);
    }
  }
}

// fused QKV projections; grid (8, 64, 3). z=0: Q, z=1: K (head-split out), z=2: V^T out.
// XCD-aware swizzle: nwg=1536, cpx=192 -> the 8 x-blocks sharing an A row-panel
// land on one XCD's L2 instead of 8 different ones.
__global__ __launch_bounds__(256) void qkv_gemm(const short* __restrict__ qb, const short* __restrict__ kb,
                                                const short* __restrict__ vb, const short* __restrict__ Wqb,
                                                const short* __restrict__ Wkb, const short* __restrict__ Wvb,
                                                short* __restrict__ Qh, short* __restrict__ Kh,
                                                short* __restrict__ VT) {
  __shared__ short As[128 * 64];
  __shared__ short Bs[128 * 64];
  const int bid = blockIdx.x + ((blockIdx.y + (blockIdx.z << 6)) << 3);
  const int swz = (bid & 7) * 192 + (bid >> 3);
  const int bx = swz & 7, by = (swz >> 3) & 63, z = swz >> 9;
  const short *A, *B; short* C;
  if (z == 0) { A = qb; B = Wqb; C = Qh; }
  else if (z == 1) { A = kb; B = Wkb; C = Kh; }
  else { A = Wvb; B = vb; C = VT; }
  const int bm = (z == 2 ? bx : by) * 128;
  const int bn = (z == 2 ? by : bx) * 128;
  f32x4 acc[4][4] = {};
  gemm_core(A, B, DD, bm, bn, As, Bs, acc);

  const int lane = threadIdx.x & 63, wave = threadIdx.x >> 6;
  const int quad = lane >> 4, l16 = lane & 15;
  const int wm = (wave >> 1) * 64, wn = (wave & 1) * 64;
#pragma unroll
  for (int mt = 0; mt < 4; ++mt)
#pragma unroll
    for (int nt = 0; nt < 4; ++nt)
#pragma unroll
      for (int i = 0; i < 4; ++i) {
        int m = bm + wm + mt * 16 + quad * 4 + i;
        int n = bn + wn + nt * 16 + l16;
        float val = acc[mt][nt][i];
        if (z < 2) {  // head-split [B,H,L,DH]
          int b = m >> 11, l = m & 2047;
          C[((size_t)(b * HH + (n >> 6)) << 17) + (size_t)l * DHD + (n & 63)] = f2bf(val);
        } else {      // V^T [B,H,DH,L]
          int b = n >> 11, l = n & 2047;
          C[((size_t)(b * DD + m) << 11) + l] = f2bf(val);
        }
      }
}

// output projection: fp32 out, grid (8, 64). nwg=512, cpx=64.
__global__ __launch_bounds__(256) void out_gemm(const short* __restrict__ A, const short* __restrict__ B,
                                                float* __restrict__ C) {
  __shared__ short As[128 * 64];
  __shared__ short Bs[128 * 64];
  const int bid = blockIdx.x + (blockIdx.y << 3);
  const int swz = (bid & 7) * 64 + (bid >> 3);
  const int bx = swz & 7, by = swz >> 3;
  const int bm = by * 128, bn = bx * 128;
  f32x4 acc[4][4] = {};
  gemm_core(A, B, DD, bm, bn, As, Bs, acc);
  const int lane = threadIdx.x & 63, wave = threadIdx.x >> 6;
  const int quad = lane >> 4, l16 = lane & 15;
  const int wm = (wave >> 1) * 64, wn = (wave & 1) * 64;
#pragma unroll
  for (int mt = 0; mt < 4; ++mt)
#pragma unroll
    for (int nt = 0; nt < 4; ++nt)
#pragma unroll
      for (int i = 0; i < 4; ++i) {
        int m = bm + wm + mt * 16 + quad * 4 + i;
        int n = bn + wn + nt * 16 + l16;
        C[(size_t)m * DD + n] = acc[mt][nt][i];
      }
}

// ---------------- flash attention, S^T formulation, max-free base-2 softmax ----
// Scores arrive pre-scaled by 0.125*log2e (folded into Wq) with the additive
// mask (-30000) as the MFMA C-operand: P = exp2(score) directly.
// Round-2 change: V is NO LONGER staged through LDS. After the XCD swizzle the
// per-head K/V (4 MB/XCD) is L2-resident, so each wave loads its V fragments
// straight from L2 (the swizzled-LDS fragment mapping reduces exactly to
// global chunk quad / 4+quad). This cuts LDS traffic per block-iter from
// ~112 KB to ~72 KB and shrinks LDS to 32 KB (Ks dbuf 16K + Pb 16K), restoring
// the grid-max 4 blocks/CU that round 1's 48 KB footprint lost.
__global__ __launch_bounds__(256, 4) void attn_kernel(const short* __restrict__ Qh,
                                                      const short* __restrict__ Kh,
                                                      const short* __restrict__ VT,
                                                      const float* __restrict__ maskadd,
                                                      short* __restrict__ AO) {
  __shared__ short Ks[2][64 * 64];
  __shared__ short Pb[4 * 2 * 16 * 64];  // [wave][u][16 q-rows][64 s], XOR-swizzled
  const int tid  = threadIdx.x;
  const int lane = tid & 63, wave = tid >> 6;
  const int wv   = __builtin_amdgcn_readfirstlane(wave);
  const int quad = lane >> 4, l16 = lane & 15;
  const int a7 = l16 & 7, q1 = quad >> 1, qlo = quad & 1;

  // XCD-aware swizzle: nwg=1024, cpx=128 -> one (b,h)'s 16 q-blocks + 8 heads
  // (exactly 4 MB of K/V) resident on one XCD's L2.
  const int bid = blockIdx.x + (blockIdx.y << 4);
  const int swz = (bid & 7) * 128 + (bid >> 3);
  const int bx = swz & 15, bh = swz >> 4;
  const int b = bh >> 4;
  const int q0 = bx * 128;

  const float* mrow = maskadd + b * LL;
  const short* Qb = Qh + (size_t)bh * LL * DHD;
  const short* Kb = Kh + (size_t)bh * LL * DHD;
  const short* Vb = VT + (size_t)bh * DHD * LL;

  s16x8 qf[2][2];
#pragma unroll
  for (int u = 0; u < 2; ++u)
#pragma unroll
    for (int c = 0; c < 2; ++c)
      qf[u][c] = *(const s16x8*)&Qb[(size_t)(q0 + wv * 32 + u * 16 + l16) * DHD + c * 32 + quad * 8];

  const short* kp[2]; int off[2];
#pragma unroll
  for (int t = 0; t < 2; ++t) {
    int s = wv * 128 + t * 64 + lane;
    int r = s >> 3, gl = (s & 7) ^ (r & 7);
    kp[t] = Kb + (size_t)r * DHD + gl * 8;
    off[t] = (wv * 128 + t * 64) * 8;
  }
  const int sw0 = (quad ^ a7) * 8;
  const int sw1 = ((4 + quad) ^ a7) * 8;
  // per-lane V base: row = l16 (d-dim), chunk quad within 64-wide s-tile
  const short* vrow = Vb + (size_t)l16 * LL + quad * 8;

  s16x8 vone;
#pragma unroll
  for (int j = 0; j < 8; ++j) vone[j] = (short)0x3F80;  // bf16 1.0

  f32x4 lsum[2] = {};
  f32x4 accO[2][4] = {};
  short* pb = &Pb[wave * 2048 + l16 * 64 + qlo * 4];

  // prologue: stage K tile 0 into buffer 0
#pragma unroll
  for (int t = 0; t < 2; ++t) gl2lds16(kp[t], &Ks[0][off[t]]);

  int cur = 0;
  for (int s0 = 0; s0 < LL; s0 += 64) {
    __syncthreads();  // drains this wave's staging loads (tile t) + releases buf^1
    if (s0 + 64 < LL) {  // issue-early: tile t+1 K loads fly under tile t's compute
#pragma unroll
      for (int t = 0; t < 2; ++t) gl2lds16(kp[t] + (size_t)(s0 + 64) * DHD, &Ks[cur ^ 1][off[t]]);
    }
    f32x4 mm[4];
#pragma unroll
    for (int st = 0; st < 4; ++st) mm[st] = *(const f32x4*)&mrow[s0 + st * 16 + quad * 4];

    const short* Kc = Ks[cur];
    s16x8 kf[4][2];
#pragma unroll
    for (int st = 0; st < 4; ++st) {
      kf[st][0] = *(const s16x8*)&Kc[(st * 16 + l16) * 64 + sw0];
      kf[st][1] = *(const s16x8*)&Kc[(st * 16 + l16) * 64 + sw1];
    }
    f32x4 sc[2][4];
    __builtin_amdgcn_s_setprio(1);
#pragma unroll
    for (int u = 0; u < 2; ++u)
#pragma unroll
      for (int st = 0; st < 4; ++st) {
        sc[u][st] = __builtin_amdgcn_mfma_f32_16x16x32_bf16(kf[st][0], qf[u][0], mm[st], 0, 0, 0);
        sc[u][st] = __builtin_amdgcn_mfma_f32_16x16x32_bf16(kf[st][1], qf[u][1], sc[u][st], 0, 0, 0);
      }
    __builtin_amdgcn_s_setprio(0);

    // V fragments straight from L2 (no LDS staging); latency hides under softmax
    s16x8 vf[4][2];
#pragma unroll
    for (int dt = 0; dt < 4; ++dt) {
      vf[dt][0] = *(const s16x8*)&vrow[(size_t)dt * 16 * LL + s0];
      vf[dt][1] = *(const s16x8*)&vrow[(size_t)dt * 16 * LL + s0 + 32];
    }

    // P = exp2(score); pack to bf16; write to Pb (A-operand layout transform)
#pragma unroll
    for (int u = 0; u < 2; ++u)
#pragma unroll
      for (int st = 0; st < 4; ++st) {
        float p0 = __builtin_amdgcn_exp2f(sc[u][st][0]);
        float p1 = __builtin_amdgcn_exp2f(sc[u][st][1]);
        float p2 = __builtin_amdgcn_exp2f(sc[u][st][2]);
        float p3 = __builtin_amdgcn_exp2f(sc[u][st][3]);
        u32x2 w; w[0] = pack2bf(p0, p1); w[1] = pack2bf(p2, p3);
        *(u32x2*)(pb + u * 1024 + (((st * 2 + q1) ^ a7) << 3)) = w;
      }

    s16x8 pf[2][2];
#pragma unroll
    for (int u = 0; u < 2; ++u)
#pragma unroll
      for (int c = 0; c < 2; ++c)
        pf[u][c] = *(const s16x8*)&Pb[(wave * 2 + u) * 1024 + l16 * 64 + (((c * 4 + quad) ^ a7) << 3)];
    __builtin_amdgcn_s_setprio(1);
#pragma unroll
    for (int u = 0; u < 2; ++u) {
      lsum[u] = __builtin_amdgcn_mfma_f32_16x16x32_bf16(pf[u][0], vone, lsum[u], 0, 0, 0);
      lsum[u] = __builtin_amdgcn_mfma_f32_16x16x32_bf16(pf[u][1], vone, lsum[u], 0, 0, 0);
    }
#pragma unroll
    for (int dt = 0; dt < 4; ++dt) {
#pragma unroll
      for (int u = 0; u < 2; ++u) {
        accO[u][dt] = __builtin_amdgcn_mfma_f32_16x16x32_bf16(pf[u][0], vf[dt][0], accO[u][dt], 0, 0, 0);
        accO[u][dt] = __builtin_amdgcn_mfma_f32_16x16x32_bf16(pf[u][1], vf[dt][1], accO[u][dt], 0, 0, 0);
      }
    }
    __builtin_amdgcn_s_setprio(0);
    cur ^= 1;
  }

  short* AOb = AO + (size_t)b * LL * DD + (size_t)(bh & 15) * DHD;
#pragma unroll
  for (int u = 0; u < 2; ++u) {
    f32x4 rl;
#pragma unroll
    for (int i = 0; i < 4; ++i) rl[i] = __builtin_amdgcn_rcpf(lsum[u][i]);
#pragma unroll
    for (int dt = 0; dt < 4; ++dt)
#pragma unroll
      for (int i = 0; i < 4; ++i) {
        int qr = q0 + wv * 32 + u * 16 + quad * 4 + i;
        AOb[(size_t)qr * DD + dt * 16 + l16] = f2bf(accO[u][dt][i] * rl[i]);
      }
  }
}

extern "C" void kernel_launch(void* const* d_in, const int* in_sizes, int n_in,
                              void* d_out, int out_size, void* d_ws, size_t ws_size,
                              hipStream_t stream) {
  const float* q   = (const float*)d_in[0];
  const float* k   = (const float*)d_in[1];
  const float* v   = (const float*)d_in[2];
  const int*  mask = (const int*)d_in[3];
  const float* Wq  = (const float*)d_in[4];
  const float* Wk  = (const float*)d_in[5];
  const float* Wv  = (const float*)d_in[6];
  const float* Wo  = (const float*)d_in[7];

  const size_t SX = (size_t)BB * LL * DD;  // 8,388,608
  const size_t SW = (size_t)DD * DD;       // 1,048,576
  short* w = (short*)d_ws;
  short* qb  = w;        short* kb  = qb + SX;  short* vb  = kb + SX;
  short* Wqb = vb + SX;  short* Wkb = Wqb + SW; short* Wvb = Wkb + SW; short* Wob = Wvb + SW;
  short* Qh  = Wob + SW; short* Kh  = Qh + SX;  short* VT  = Kh + SX;
  float* maskadd = (float*)(VT + SX);
  short* AO = qb;  // qb dead after QKV projections

  prep_kernel<<<28680, 256, 0, stream>>>(q, k, v, Wq, Wk, Wv, Wo, mask,
                                         qb, kb, vb, Wqb, Wkb, Wvb, Wob, maskadd);
  qkv_gemm<<<dim3(8, 64, 3), 256, 0, stream>>>(qb, kb, vb, Wqb, Wkb, Wvb, Qh, Kh, VT);
  attn_kernel<<<dim3(LL / 128, BB * HH), 256, 0, stream>>>(Qh, Kh, VT, maskadd, AO);
  out_gemm<<<dim3(8, 64), 256, 0, stream>>>(AO, Wob, (float*)d_out);
}

// Round 3
// 332.918 us; speedup vs baseline: 1.4676x; 1.4676x over previous
//
#include <hip/hip_runtime.h>
#include <cstddef>
#include <cstdint>

#define BB 4
#define LL 2048
#define DD 1024
#define HH 16
#define DHD 64
#define QSCALE 0.18033688f  // 0.125 * log2(e): softmax in base-2 domain

typedef short s16x8 __attribute__((ext_vector_type(8)));
typedef short s16x4 __attribute__((ext_vector_type(4)));
typedef float f32x4 __attribute__((ext_vector_type(4)));
typedef unsigned int u32;
typedef u32 u32x2 __attribute__((ext_vector_type(2)));
typedef u32 u32x4 __attribute__((ext_vector_type(4)));

__device__ __forceinline__ short f2bf(float f) {
  union { float f; u32 u; } x; x.f = f;
  u32 r = x.u + 0x7FFFu + ((x.u >> 16) & 1u);
  return (short)(r >> 16);
}
// pack two f32 -> two bf16 (round-half-up) in one v_perm
__device__ __forceinline__ u32 pack2bf(float a, float b) {
  union { float f; u32 u; } x, y; x.f = a; y.f = b;
  return __builtin_amdgcn_perm(y.u + 0x8000u, x.u + 0x8000u, 0x07060302u);
}
__device__ __forceinline__ void gl2lds16(const short* g, short* l) {
  __builtin_amdgcn_global_load_lds(
      (const __attribute__((address_space(1))) unsigned int*)g,
      (__attribute__((address_space(3))) unsigned int*)l, 16, 0, 0);
}

// ---------------- merged prep: casts + mask (one launch instead of three) ----
__global__ __launch_bounds__(256) void prep_kernel(const float* __restrict__ q,
                                                   const float* __restrict__ k,
                                                   const float* __restrict__ v,
                                                   const float* __restrict__ Wq,
                                                   const float* __restrict__ Wk,
                                                   const float* __restrict__ Wv,
                                                   const float* __restrict__ Wo,
                                                   const int* __restrict__ mask,
                                                   short* __restrict__ qb,
                                                   short* __restrict__ kb,
                                                   short* __restrict__ vb,
                                                   short* __restrict__ Wqb,
                                                   short* __restrict__ Wkb,
                                                   short* __restrict__ Wvb,
                                                   short* __restrict__ Wob,
                                                   float* __restrict__ maskadd) {
  const int bb = blockIdx.x;
  if (bb < 24576) {
    const float* s; short* d;
    const int y = bb >> 13;
    if (y == 0) { s = q; d = qb; }
    else if (y == 1) { s = k; d = kb; }
    else { s = v; d = vb; }
    int i = (bb & 8191) * 256 + threadIdx.x;
    float4 x = ((const float4*)s)[i];
    s16x4 o; o.x = f2bf(x.x); o.y = f2bf(x.y); o.z = f2bf(x.z); o.w = f2bf(x.w);
    ((s16x4*)d)[i] = o;
  } else if (bb < 28672) {
    const int y = (bb - 24576) >> 10;
    const float* s; short* d; float sc = 1.0f;
    if (y == 0) { s = Wq; d = Wqb; sc = QSCALE; }
    else if (y == 1) { s = Wk; d = Wkb; }
    else if (y == 2) { s = Wv; d = Wvb; }
    else { s = Wo; d = Wob; }
    int i = ((bb - 24576) & 1023) * 256 + threadIdx.x;
    float4 x = ((const float4*)s)[i];
    s16x4 o; o.x = f2bf(x.x * sc); o.y = f2bf(x.y * sc); o.z = f2bf(x.z * sc); o.w = f2bf(x.w * sc);
    ((s16x4*)d)[i] = o;
  } else {
    int i = (bb - 28672) * 256 + threadIdx.x;
    int4 m = ((const int4*)mask)[i];
    f32x4 o;
    o[0] = (m.x == 1) ? 0.0f : -30000.0f;
    o[1] = (m.y == 1) ? 0.0f : -30000.0f;
    o[2] = (m.z == 1) ? 0.0f : -30000.0f;
    o[3] = (m.w == 1) ? 0.0f : -30000.0f;
    ((f32x4*)maskadd)[i] = o;
  }
}

// ---------------- shared GEMM core (128x128 tile, bt layout) ----------------
__device__ __forceinline__ void gemm_core(const short* __restrict__ A, const short* __restrict__ B,
                                          int K, int bm, int bn, short* As, short* Bs,
                                          f32x4 (&acc)[4][4]) {
  const int tid = threadIdx.x;
  const int lane = tid & 63, wave = tid >> 6;
  const int wv = __builtin_amdgcn_readfirstlane(wave);
  const int quad = lane >> 4, l16 = lane & 15;
  const int wm = (wave >> 1) * 64, wn = (wave & 1) * 64;
  const short* ap[4]; const short* bp[4]; short* la[4]; short* lb[4];
#pragma unroll
  for (int t = 0; t < 4; ++t) {
    int s = wv * 256 + t * 64 + lane;
    int r = s >> 3, gl = (s & 7) ^ (r & 7);
    ap[t] = A + (size_t)(bm + r) * K + gl * 8;
    bp[t] = B + (size_t)(bn + r) * K + gl * 8;
    la[t] = &As[(wv * 256 + t * 64) * 8];
    lb[t] = &Bs[(wv * 256 + t * 64) * 8];
  }
  const int sw0 = (quad ^ (l16 & 7)) * 8;
  const int sw1 = ((4 + quad) ^ (l16 & 7)) * 8;
  for (int kk = 0; kk < K; kk += 64) {
    __syncthreads();
#pragma unroll
    for (int t = 0; t < 4; ++t) gl2lds16(ap[t] + kk, la[t]);
#pragma unroll
    for (int t = 0; t < 4; ++t) gl2lds16(bp[t] + kk, lb[t]);
    __syncthreads();
#pragma unroll
    for (int c = 0; c < 2; ++c) {
      const int sw = c ? sw1 : sw0;
      s16x8 af[4], bf[4];
#pragma unroll
      for (int t = 0; t < 4; ++t) af[t] = *(const s16x8*)&As[(wm + t * 16 + l16) * 64 + sw];
#pragma unroll
      for (int t = 0; t < 4; ++t) bf[t] = *(const s16x8*)&Bs[(wn + t * 16 + l16) * 64 + sw];
      __builtin_amdgcn_s_setprio(1);
#pragma unroll
      for (int mt = 0; mt < 4; ++mt)
#pragma unroll
        for (int nt = 0; nt < 4; ++nt)
          acc[mt][nt] = __builtin_amdgcn_mfma_f32_16x16x32_bf16(af[mt], bf[nt], acc[mt][nt], 0, 0, 0);
      __builtin_amdgcn_s_setprio(0);
    }
  }
}

// fused QKV projections; grid (8, 64, 3). z=0: Q, z=1: K (head-split out), z=2: V^T out.
__global__ __launch_bounds__(256) void qkv_gemm(const short* __restrict__ qb, const short* __restrict__ kb,
                                                const short* __restrict__ vb, const short* __restrict__ Wqb,
                                                const short* __restrict__ Wkb, const short* __restrict__ Wvb,
                                                short* __restrict__ Qh, short* __restrict__ Kh,
                                                short* __restrict__ VT) {
  __shared__ short As[128 * 64];
  __shared__ short Bs[128 * 64];
  const int bid = blockIdx.x + ((blockIdx.y + (blockIdx.z << 6)) << 3);
  const int swz = (bid & 7) * 192 + (bid >> 3);
  const int bx = swz & 7, by = (swz >> 3) & 63, z = swz >> 9;
  const short *A, *B; short* C;
  if (z == 0) { A = qb; B = Wqb; C = Qh; }
  else if (z == 1) { A = kb; B = Wkb; C = Kh; }
  else { A = Wvb; B = vb; C = VT; }
  const int bm = (z == 2 ? bx : by) * 128;
  const int bn = (z == 2 ? by : bx) * 128;
  f32x4 acc[4][4] = {};
  gemm_core(A, B, DD, bm, bn, As, Bs, acc);

  const int lane = threadIdx.x & 63, wave = threadIdx.x >> 6;
  const int quad = lane >> 4, l16 = lane & 15;
  const int wm = (wave >> 1) * 64, wn = (wave & 1) * 64;
#pragma unroll
  for (int mt = 0; mt < 4; ++mt)
#pragma unroll
    for (int nt = 0; nt < 4; ++nt)
#pragma unroll
      for (int i = 0; i < 4; ++i) {
        int m = bm + wm + mt * 16 + quad * 4 + i;
        int n = bn + wn + nt * 16 + l16;
        float val = acc[mt][nt][i];
        if (z < 2) {  // head-split [B,H,L,DH]
          int b = m >> 11, l = m & 2047;
          C[((size_t)(b * HH + (n >> 6)) << 17) + (size_t)l * DHD + (n & 63)] = f2bf(val);
        } else {      // V^T [B,H,DH,L]
          int b = n >> 11, l = n & 2047;
          C[((size_t)(b * DD + m) << 11) + l] = f2bf(val);
        }
      }
}

// output projection: fp32 out, grid (8, 64). nwg=512, cpx=64.
__global__ __launch_bounds__(256) void out_gemm(const short* __restrict__ A, const short* __restrict__ B,
                                                float* __restrict__ C) {
  __shared__ short As[128 * 64];
  __shared__ short Bs[128 * 64];
  const int bid = blockIdx.x + (blockIdx.y << 3);
  const int swz = (bid & 7) * 64 + (bid >> 3);
  const int bx = swz & 7, by = swz >> 3;
  const int bm = by * 128, bn = bx * 128;
  f32x4 acc[4][4] = {};
  gemm_core(A, B, DD, bm, bn, As, Bs, acc);
  const int lane = threadIdx.x & 63, wave = threadIdx.x >> 6;
  const int quad = lane >> 4, l16 = lane & 15;
  const int wm = (wave >> 1) * 64, wn = (wave & 1) * 64;
#pragma unroll
  for (int mt = 0; mt < 4; ++mt)
#pragma unroll
    for (int nt = 0; nt < 4; ++nt)
#pragma unroll
      for (int i = 0; i < 4; ++i) {
        int m = bm + wm + mt * 16 + quad * 4 + i;
        int n = bn + wn + nt * 16 + l16;
        C[(size_t)m * DD + n] = acc[mt][nt][i];
      }
}

// ---------------- flash attention, S^T formulation, max-free base-2 softmax ----
// Round-3 change: the P-layout transform through LDS (Pb) is ELIMINATED.
// MFMA's k-order is arbitrary if A and B use the same permutation (the row-sum
// via vone is order-independent). Choosing k=quad*8+j <-> s=32c+(j>>2)*16+
// quad*4+(j&3) makes the A-fragment pf[u][c] exactly the lane's own sc[u][2c],
// sc[u][2c+1] packed to bf16 -- a pure register pack, no cross-lane ops.
// The matching V fragment is two ds_read_b64 at half-granule offsets of the
// XOR-swizzled Vs tile (2 lanes/bank = conflict-free). LDS drops to 32 KB
// (Ks+Vs both double-buffered) -> 4 blocks/CU WITH the single-barrier
// issue-early pipeline. V staging is restored (round-2's direct-L2 V thrashed:
// FETCH 24.6 -> 129 MB).
__global__ __launch_bounds__(256, 4) void attn_kernel(const short* __restrict__ Qh,
                                                      const short* __restrict__ Kh,
                                                      const short* __restrict__ VT,
                                                      const float* __restrict__ maskadd,
                                                      short* __restrict__ AO) {
  __shared__ short Ks[2][64 * 64];
  __shared__ short Vs[2][64 * 64];
  const int tid  = threadIdx.x;
  const int lane = tid & 63, wave = tid >> 6;
  const int wv   = __builtin_amdgcn_readfirstlane(wave);
  const int quad = lane >> 4, l16 = lane & 15;
  const int a7 = l16 & 7, qh = quad >> 1, ql = quad & 1;

  // XCD-aware swizzle: nwg=1024, cpx=128 -> one XCD serves 8 heads (4 MB K/V).
  const int bid = blockIdx.x + (blockIdx.y << 4);
  const int swz = (bid & 7) * 128 + (bid >> 3);
  const int bx = swz & 15, bh = swz >> 4;
  const int b = bh >> 4;
  const int q0 = bx * 128;

  const float* mrow = maskadd + b * LL;
  const short* Qb = Qh + (size_t)bh * LL * DHD;
  const short* Kb = Kh + (size_t)bh * LL * DHD;
  const short* Vb = VT + (size_t)bh * DHD * LL;

  s16x8 qf[2][2];
#pragma unroll
  for (int u = 0; u < 2; ++u)
#pragma unroll
    for (int c = 0; c < 2; ++c)
      qf[u][c] = *(const s16x8*)&Qb[(size_t)(q0 + wv * 32 + u * 16 + l16) * DHD + c * 32 + quad * 8];

  const short* kp[2]; const short* vp[2]; int off[2];
#pragma unroll
  for (int t = 0; t < 2; ++t) {
    int s = wv * 128 + t * 64 + lane;
    int r = s >> 3, gl = (s & 7) ^ (r & 7);
    kp[t] = Kb + (size_t)r * DHD + gl * 8;
    vp[t] = Vb + (size_t)r * LL + gl * 8;
    off[t] = (wv * 128 + t * 64) * 8;
  }
  const int sw0 = (quad ^ a7) * 8;
  const int sw1 = ((4 + quad) ^ a7) * 8;

  s16x8 vone;
#pragma unroll
  for (int j = 0; j < 8; ++j) vone[j] = (short)0x3F80;  // bf16 1.0

  f32x4 lsum[2] = {};
  f32x4 accO[2][4] = {};

  // prologue: stage tile 0 into buffer 0
#pragma unroll
  for (int t = 0; t < 2; ++t) gl2lds16(kp[t], &Ks[0][off[t]]);
#pragma unroll
  for (int t = 0; t < 2; ++t) gl2lds16(vp[t], &Vs[0][off[t]]);

  int cur = 0;
  for (int s0 = 0; s0 < LL; s0 += 64) {
    __syncthreads();  // drains staging of tile t + releases buf^1
    if (s0 + 64 < LL) {  // issue-early: tile t+1 loads fly under tile t's compute
#pragma unroll
      for (int t = 0; t < 2; ++t) gl2lds16(kp[t] + (size_t)(s0 + 64) * DHD, &Ks[cur ^ 1][off[t]]);
#pragma unroll
      for (int t = 0; t < 2; ++t) gl2lds16(vp[t] + (s0 + 64), &Vs[cur ^ 1][off[t]]);
    }
    f32x4 mm[4];
#pragma unroll
    for (int st = 0; st < 4; ++st) mm[st] = *(const f32x4*)&mrow[s0 + st * 16 + quad * 4];

    const short* Kc = Ks[cur];
    const short* Vc = Vs[cur];
    s16x8 kf[4][2];
#pragma unroll
    for (int st = 0; st < 4; ++st) {
      kf[st][0] = *(const s16x8*)&Kc[(st * 16 + l16) * 64 + sw0];
      kf[st][1] = *(const s16x8*)&Kc[(st * 16 + l16) * 64 + sw1];
    }
    f32x4 sc[2][4];
    __builtin_amdgcn_s_setprio(1);
#pragma unroll
    for (int u = 0; u < 2; ++u)
#pragma unroll
      for (int st = 0; st < 4; ++st) {
        sc[u][st] = __builtin_amdgcn_mfma_f32_16x16x32_bf16(kf[st][0], qf[u][0], mm[st], 0, 0, 0);
        sc[u][st] = __builtin_amdgcn_mfma_f32_16x16x32_bf16(kf[st][1], qf[u][1], sc[u][st], 0, 0, 0);
      }
    __builtin_amdgcn_s_setprio(0);

    // P = exp2(score), packed straight into the PV A-fragment (permuted k-order)
    s16x8 pf[2][2];
#pragma unroll
    for (int u = 0; u < 2; ++u)
#pragma unroll
      for (int c = 0; c < 2; ++c) {
        union { u32x4 u4; s16x8 s8; } cv;
#pragma unroll
        for (int h = 0; h < 2; ++h) {
          const int st = 2 * c + h;
          float p0 = __builtin_amdgcn_exp2f(sc[u][st][0]);
          float p1 = __builtin_amdgcn_exp2f(sc[u][st][1]);
          float p2 = __builtin_amdgcn_exp2f(sc[u][st][2]);
          float p3 = __builtin_amdgcn_exp2f(sc[u][st][3]);
          cv.u4[h * 2 + 0] = pack2bf(p0, p1);
          cv.u4[h * 2 + 1] = pack2bf(p2, p3);
        }
        pf[u][c] = cv.s8;
      }

    __builtin_amdgcn_s_setprio(1);
#pragma unroll
    for (int u = 0; u < 2; ++u) {
      lsum[u] = __builtin_amdgcn_mfma_f32_16x16x32_bf16(pf[u][0], vone, lsum[u], 0, 0, 0);
      lsum[u] = __builtin_amdgcn_mfma_f32_16x16x32_bf16(pf[u][1], vone, lsum[u], 0, 0, 0);
    }
#pragma unroll
    for (int dt = 0; dt < 4; ++dt) {
      const int drow = (dt * 16 + l16) * 64;
#pragma unroll
      for (int c = 0; c < 2; ++c) {
        // V fragment in the permuted k-order: element j = V^T[d][32c+(j>>2)*16+quad*4+(j&3)]
        union { s16x4 h[2]; s16x8 v; } vv;
        vv.h[0] = *(const s16x4*)&Vc[drow + (((c * 4 + qh) ^ a7) << 3) + ql * 4];
        vv.h[1] = *(const s16x4*)&Vc[drow + (((c * 4 + 2 + qh) ^ a7) << 3) + ql * 4];
#pragma unroll
        for (int u = 0; u < 2; ++u)
          accO[u][dt] = __builtin_amdgcn_mfma_f32_16x16x32_bf16(pf[u][c], vv.v, accO[u][dt], 0, 0, 0);
      }
    }
    __builtin_amdgcn_s_setprio(0);
    cur ^= 1;
  }

  short* AOb = AO + (size_t)b * LL * DD + (size_t)(bh & 15) * DHD;
#pragma unroll
  for (int u = 0; u < 2; ++u) {
    f32x4 rl;
#pragma unroll
    for (int i = 0; i < 4; ++i) rl[i] = __builtin_amdgcn_rcpf(lsum[u][i]);
#pragma unroll
    for (int dt = 0; dt < 4; ++dt)
#pragma unroll
      for (int i = 0; i < 4; ++i) {
        int qr = q0 + wv * 32 + u * 16 + quad * 4 + i;
        AOb[(size_t)qr * DD + dt * 16 + l16] = f2bf(accO[u][dt][i] * rl[i]);
      }
  }
}

extern "C" void kernel_launch(void* const* d_in, const int* in_sizes, int n_in,
                              void* d_out, int out_size, void* d_ws, size_t ws_size,
                              hipStream_t stream) {
  const float* q   = (const float*)d_in[0];
  const float* k   = (const float*)d_in[1];
  const float* v   = (const float*)d_in[2];
  const int*  mask = (const int*)d_in[3];
  const float* Wq  = (const float*)d_in[4];
  const float* Wk  = (const float*)d_in[5];
  const float* Wv  = (const float*)d_in[6];
  const float* Wo  = (const float*)d_in[7];

  const size_t SX = (size_t)BB * LL * DD;  // 8,388,608
  const size_t SW = (size_t)DD * DD;       // 1,048,576
  short* w = (short*)d_ws;
  short* qb  = w;        short* kb  = qb + SX;  short* vb  = kb + SX;
  short* Wqb = vb + SX;  short* Wkb = Wqb + SW; short* Wvb = Wkb + SW; short* Wob = Wvb + SW;
  short* Qh  = Wob + SW; short* Kh  = Qh + SX;  short* VT  = Kh + SX;
  float* maskadd = (float*)(VT + SX);
  short* AO = qb;  // qb dead after QKV projections

  prep_kernel<<<28680, 256, 0, stream>>>(q, k, v, Wq, Wk, Wv, Wo, mask,
                                         qb, kb, vb, Wqb, Wkb, Wvb, Wob, maskadd);
  qkv_gemm<<<dim3(8, 64, 3), 256, 0, stream>>>(qb, kb, vb, Wqb, Wkb, Wvb, Qh, Kh, VT);
  attn_kernel<<<dim3(LL / 128, BB * HH), 256, 0, stream>>>(Qh, Kh, VT, maskadd, AO);
  out_gemm<<<dim3(8, 64), 256, 0, stream>>>(AO, Wob, (float*)d_out);
}

// Round 4
// 311.988 us; speedup vs baseline: 1.5661x; 1.0671x over previous
//
#include <hip/hip_runtime.h>
#include <cstddef>
#include <cstdint>

#define BB 4
#define LL 2048
#define DD 1024
#define HH 16
#define DHD 64
#define QSCALE 0.18033688f  // 0.125 * log2(e): softmax in base-2 domain

typedef short s16x8 __attribute__((ext_vector_type(8)));
typedef short s16x4 __attribute__((ext_vector_type(4)));
typedef float f32x4 __attribute__((ext_vector_type(4)));
typedef unsigned int u32;
typedef u32 u32x2 __attribute__((ext_vector_type(2)));
typedef u32 u32x4 __attribute__((ext_vector_type(4)));

__device__ __forceinline__ short f2bf(float f) {
  union { float f; u32 u; } x; x.f = f;
  u32 r = x.u + 0x7FFFu + ((x.u >> 16) & 1u);
  return (short)(r >> 16);
}
// pack two f32 -> two bf16 (round-half-up) in one v_perm
__device__ __forceinline__ u32 pack2bf(float a, float b) {
  union { float f; u32 u; } x, y; x.f = a; y.f = b;
  return __builtin_amdgcn_perm(y.u + 0x8000u, x.u + 0x8000u, 0x07060302u);
}
// hardware packed f32x2 -> bf16x2 (RNE); no builtin on gfx950, asm per T12
__device__ __forceinline__ u32 cvtpk2bf(float lo, float hi) {
  u32 r;
  asm("v_cvt_pk_bf16_f32 %0, %1, %2" : "=v"(r) : "v"(lo), "v"(hi));
  return r;
}
__device__ __forceinline__ void gl2lds16(const short* g, short* l) {
  __builtin_amdgcn_global_load_lds(
      (const __attribute__((address_space(1))) unsigned int*)g,
      (__attribute__((address_space(3))) unsigned int*)l, 16, 0, 0);
}

// ---------------- merged prep: casts + mask (one launch instead of three) ----
__global__ __launch_bounds__(256) void prep_kernel(const float* __restrict__ q,
                                                   const float* __restrict__ k,
                                                   const float* __restrict__ v,
                                                   const float* __restrict__ Wq,
                                                   const float* __restrict__ Wk,
                                                   const float* __restrict__ Wv,
                                                   const float* __restrict__ Wo,
                                                   const int* __restrict__ mask,
                                                   short* __restrict__ qb,
                                                   short* __restrict__ kb,
                                                   short* __restrict__ vb,
                                                   short* __restrict__ Wqb,
                                                   short* __restrict__ Wkb,
                                                   short* __restrict__ Wvb,
                                                   short* __restrict__ Wob,
                                                   float* __restrict__ maskadd) {
  const int bb = blockIdx.x;
  if (bb < 24576) {
    const float* s; short* d;
    const int y = bb >> 13;
    if (y == 0) { s = q; d = qb; }
    else if (y == 1) { s = k; d = kb; }
    else { s = v; d = vb; }
    int i = (bb & 8191) * 256 + threadIdx.x;
    float4 x = ((const float4*)s)[i];
    s16x4 o; o.x = f2bf(x.x); o.y = f2bf(x.y); o.z = f2bf(x.z); o.w = f2bf(x.w);
    ((s16x4*)d)[i] = o;
  } else if (bb < 28672) {
    const int y = (bb - 24576) >> 10;
    const float* s; short* d; float sc = 1.0f;
    if (y == 0) { s = Wq; d = Wqb; sc = QSCALE; }
    else if (y == 1) { s = Wk; d = Wkb; }
    else if (y == 2) { s = Wv; d = Wvb; }
    else { s = Wo; d = Wob; }
    int i = ((bb - 24576) & 1023) * 256 + threadIdx.x;
    float4 x = ((const float4*)s)[i];
    s16x4 o; o.x = f2bf(x.x * sc); o.y = f2bf(x.y * sc); o.z = f2bf(x.z * sc); o.w = f2bf(x.w * sc);
    ((s16x4*)d)[i] = o;
  } else {
    int i = (bb - 28672) * 256 + threadIdx.x;
    int4 m = ((const int4*)mask)[i];
    f32x4 o;
    o[0] = (m.x == 1) ? 0.0f : -30000.0f;
    o[1] = (m.y == 1) ? 0.0f : -30000.0f;
    o[2] = (m.z == 1) ? 0.0f : -30000.0f;
    o[3] = (m.w == 1) ? 0.0f : -30000.0f;
    ((f32x4*)maskadd)[i] = o;
  }
}

// ---------------- shared GEMM core (128x128 tile, bt layout) ----------------
__device__ __forceinline__ void gemm_core(const short* __restrict__ A, const short* __restrict__ B,
                                          int K, int bm, int bn, short* As, short* Bs,
                                          f32x4 (&acc)[4][4]) {
  const int tid = threadIdx.x;
  const int lane = tid & 63, wave = tid >> 6;
  const int wv = __builtin_amdgcn_readfirstlane(wave);
  const int quad = lane >> 4, l16 = lane & 15;
  const int wm = (wave >> 1) * 64, wn = (wave & 1) * 64;
  const short* ap[4]; const short* bp[4]; short* la[4]; short* lb[4];
#pragma unroll
  for (int t = 0; t < 4; ++t) {
    int s = wv * 256 + t * 64 + lane;
    int r = s >> 3, gl = (s & 7) ^ (r & 7);
    ap[t] = A + (size_t)(bm + r) * K + gl * 8;
    bp[t] = B + (size_t)(bn + r) * K + gl * 8;
    la[t] = &As[(wv * 256 + t * 64) * 8];
    lb[t] = &Bs[(wv * 256 + t * 64) * 8];
  }
  const int sw0 = (quad ^ (l16 & 7)) * 8;
  const int sw1 = ((4 + quad) ^ (l16 & 7)) * 8;
  for (int kk = 0; kk < K; kk += 64) {
    __syncthreads();
#pragma unroll
    for (int t = 0; t < 4; ++t) gl2lds16(ap[t] + kk, la[t]);
#pragma unroll
    for (int t = 0; t < 4; ++t) gl2lds16(bp[t] + kk, lb[t]);
    __syncthreads();
#pragma unroll
    for (int c = 0; c < 2; ++c) {
      const int sw = c ? sw1 : sw0;
      s16x8 af[4], bf[4];
#pragma unroll
      for (int t = 0; t < 4; ++t) af[t] = *(const s16x8*)&As[(wm + t * 16 + l16) * 64 + sw];
#pragma unroll
      for (int t = 0; t < 4; ++t) bf[t] = *(const s16x8*)&Bs[(wn + t * 16 + l16) * 64 + sw];
      __builtin_amdgcn_s_setprio(1);
#pragma unroll
      for (int mt = 0; mt < 4; ++mt)
#pragma unroll
        for (int nt = 0; nt < 4; ++nt)
          acc[mt][nt] = __builtin_amdgcn_mfma_f32_16x16x32_bf16(af[mt], bf[nt], acc[mt][nt], 0, 0, 0);
      __builtin_amdgcn_s_setprio(0);
    }
  }
}

// fused QKV projections; grid (8, 64, 3). z=0: Q, z=1: K (head-split out), z=2: V^T out.
__global__ __launch_bounds__(256) void qkv_gemm(const short* __restrict__ qb, const short* __restrict__ kb,
                                                const short* __restrict__ vb, const short* __restrict__ Wqb,
                                                const short* __restrict__ Wkb, const short* __restrict__ Wvb,
                                                short* __restrict__ Qh, short* __restrict__ Kh,
                                                short* __restrict__ VT) {
  __shared__ short As[128 * 64];
  __shared__ short Bs[128 * 64];
  const int bid = blockIdx.x + ((blockIdx.y + (blockIdx.z << 6)) << 3);
  const int swz = (bid & 7) * 192 + (bid >> 3);
  const int bx = swz & 7, by = (swz >> 3) & 63, z = swz >> 9;
  const short *A, *B; short* C;
  if (z == 0) { A = qb; B = Wqb; C = Qh; }
  else if (z == 1) { A = kb; B = Wkb; C = Kh; }
  else { A = Wvb; B = vb; C = VT; }
  const int bm = (z == 2 ? bx : by) * 128;
  const int bn = (z == 2 ? by : bx) * 128;
  f32x4 acc[4][4] = {};
  gemm_core(A, B, DD, bm, bn, As, Bs, acc);

  const int lane = threadIdx.x & 63, wave = threadIdx.x >> 6;
  const int quad = lane >> 4, l16 = lane & 15;
  const int wm = (wave >> 1) * 64, wn = (wave & 1) * 64;
#pragma unroll
  for (int mt = 0; mt < 4; ++mt)
#pragma unroll
    for (int nt = 0; nt < 4; ++nt)
#pragma unroll
      for (int i = 0; i < 4; ++i) {
        int m = bm + wm + mt * 16 + quad * 4 + i;
        int n = bn + wn + nt * 16 + l16;
        float val = acc[mt][nt][i];
        if (z < 2) {  // head-split [B,H,L,DH]
          int b = m >> 11, l = m & 2047;
          C[((size_t)(b * HH + (n >> 6)) << 17) + (size_t)l * DHD + (n & 63)] = f2bf(val);
        } else {      // V^T [B,H,DH,L], s-permuted within each 64-token group:
          // storage pos p = {s5,s3,s2,s4,s1,s0} so attn's PV k-order fragment
          // is one contiguous 16B chunk (single swizzled ds_read_b128).
          int b = n >> 11, l = n & 2047;
          int loc = l & 63;
          int p = (loc & 0x23) | ((loc & 0x0C) << 1) | ((loc & 0x10) >> 2);
          C[((size_t)(b * DD + m) << 11) + (l & ~63) + p] = f2bf(val);
        }
      }
}

// output projection: fp32 out, grid (8, 64). nwg=512, cpx=64.
__global__ __launch_bounds__(256) void out_gemm(const short* __restrict__ A, const short* __restrict__ B,
                                                float* __restrict__ C) {
  __shared__ short As[128 * 64];
  __shared__ short Bs[128 * 64];
  const int bid = blockIdx.x + (blockIdx.y << 3);
  const int swz = (bid & 7) * 64 + (bid >> 3);
  const int bx = swz & 7, by = swz >> 3;
  const int bm = by * 128, bn = bx * 128;
  f32x4 acc[4][4] = {};
  gemm_core(A, B, DD, bm, bn, As, Bs, acc);
  const int lane = threadIdx.x & 63, wave = threadIdx.x >> 6;
  const int quad = lane >> 4, l16 = lane & 15;
  const int wm = (wave >> 1) * 64, wn = (wave & 1) * 64;
#pragma unroll
  for (int mt = 0; mt < 4; ++mt)
#pragma unroll
    for (int nt = 0; nt < 4; ++nt)
#pragma unroll
      for (int i = 0; i < 4; ++i) {
        int m = bm + wm + mt * 16 + quad * 4 + i;
        int n = bn + wn + nt * 16 + l16;
        C[(size_t)m * DD + n] = acc[mt][nt][i];
      }
}

// ---------------- flash attention, S^T formulation, max-free base-2 softmax ----
// Round-4 changes vs round 3:
//  (a) VT arrives pre-permuted (see qkv_gemm) so the PV V-fragment is ONE
//      swizzled ds_read_b128 — same conflict-free pattern as kf (round-3's
//      split b64 pair was a 4-way bank conflict, +4.2M conflict-cycles).
//  (b) P pack uses v_cvt_pk_bf16_f32 (1 instr/pair vs perm+2add) — VALU was
//      the busier pipe (42% vs MFMA 30%).
//  (c) s_setprio removed: all waves are barrier-lockstep, T5 prereq absent
//      (measured null-to-negative on lockstep structures, m190).
__global__ __launch_bounds__(256, 4) void attn_kernel(const short* __restrict__ Qh,
                                                      const short* __restrict__ Kh,
                                                      const short* __restrict__ VT,
                                                      const float* __restrict__ maskadd,
                                                      short* __restrict__ AO) {
  __shared__ short Ks[2][64 * 64];
  __shared__ short Vs[2][64 * 64];
  const int tid  = threadIdx.x;
  const int lane = tid & 63, wave = tid >> 6;
  const int wv   = __builtin_amdgcn_readfirstlane(wave);
  const int quad = lane >> 4, l16 = lane & 15;
  const int a7 = l16 & 7;

  // XCD-aware swizzle: nwg=1024, cpx=128 -> one XCD serves 8 heads (4 MB K/V).
  const int bid = blockIdx.x + (blockIdx.y << 4);
  const int swz = (bid & 7) * 128 + (bid >> 3);
  const int bx = swz & 15, bh = swz >> 4;
  const int b = bh >> 4;
  const int q0 = bx * 128;

  const float* mrow = maskadd + b * LL;
  const short* Qb = Qh + (size_t)bh * LL * DHD;
  const short* Kb = Kh + (size_t)bh * LL * DHD;
  const short* Vb = VT + (size_t)bh * DHD * LL;

  s16x8 qf[2][2];
#pragma unroll
  for (int u = 0; u < 2; ++u)
#pragma unroll
    for (int c = 0; c < 2; ++c)
      qf[u][c] = *(const s16x8*)&Qb[(size_t)(q0 + wv * 32 + u * 16 + l16) * DHD + c * 32 + quad * 8];

  const short* kp[2]; const short* vp[2]; int off[2];
#pragma unroll
  for (int t = 0; t < 2; ++t) {
    int s = wv * 128 + t * 64 + lane;
    int r = s >> 3, gl = (s & 7) ^ (r & 7);
    kp[t] = Kb + (size_t)r * DHD + gl * 8;
    vp[t] = Vb + (size_t)r * LL + gl * 8;
    off[t] = (wv * 128 + t * 64) * 8;
  }
  const int sw0 = (quad ^ a7) * 8;
  const int sw1 = ((4 + quad) ^ a7) * 8;

  s16x8 vone;
#pragma unroll
  for (int j = 0; j < 8; ++j) vone[j] = (short)0x3F80;  // bf16 1.0

  f32x4 lsum[2] = {};
  f32x4 accO[2][4] = {};

  // prologue: stage tile 0 into buffer 0
#pragma unroll
  for (int t = 0; t < 2; ++t) gl2lds16(kp[t], &Ks[0][off[t]]);
#pragma unroll
  for (int t = 0; t < 2; ++t) gl2lds16(vp[t], &Vs[0][off[t]]);

  int cur = 0;
  for (int s0 = 0; s0 < LL; s0 += 64) {
    __syncthreads();  // drains staging of tile t + releases buf^1
    if (s0 + 64 < LL) {  // issue-early: tile t+1 loads fly under tile t's compute
#pragma unroll
      for (int t = 0; t < 2; ++t) gl2lds16(kp[t] + (size_t)(s0 + 64) * DHD, &Ks[cur ^ 1][off[t]]);
#pragma unroll
      for (int t = 0; t < 2; ++t) gl2lds16(vp[t] + (s0 + 64), &Vs[cur ^ 1][off[t]]);
    }
    f32x4 mm[4];
#pragma unroll
    for (int st = 0; st < 4; ++st) mm[st] = *(const f32x4*)&mrow[s0 + st * 16 + quad * 4];

    const short* Kc = Ks[cur];
    const short* Vc = Vs[cur];
    s16x8 kf[4][2];
#pragma unroll
    for (int st = 0; st < 4; ++st) {
      kf[st][0] = *(const s16x8*)&Kc[(st * 16 + l16) * 64 + sw0];
      kf[st][1] = *(const s16x8*)&Kc[(st * 16 + l16) * 64 + sw1];
    }
    f32x4 sc[2][4];
#pragma unroll
    for (int u = 0; u < 2; ++u)
#pragma unroll
      for (int st = 0; st < 4; ++st) {
        sc[u][st] = __builtin_amdgcn_mfma_f32_16x16x32_bf16(kf[st][0], qf[u][0], mm[st], 0, 0, 0);
        sc[u][st] = __builtin_amdgcn_mfma_f32_16x16x32_bf16(kf[st][1], qf[u][1], sc[u][st], 0, 0, 0);
      }

    // P = exp2(score), packed straight into the PV A-fragment (permuted k-order)
    s16x8 pf[2][2];
#pragma unroll
    for (int u = 0; u < 2; ++u)
#pragma unroll
      for (int c = 0; c < 2; ++c) {
        union { u32x4 u4; s16x8 s8; } cv;
#pragma unroll
        for (int h = 0; h < 2; ++h) {
          const int st = 2 * c + h;
          float p0 = __builtin_amdgcn_exp2f(sc[u][st][0]);
          float p1 = __builtin_amdgcn_exp2f(sc[u][st][1]);
          float p2 = __builtin_amdgcn_exp2f(sc[u][st][2]);
          float p3 = __builtin_amdgcn_exp2f(sc[u][st][3]);
          cv.u4[h * 2 + 0] = cvtpk2bf(p0, p1);
          cv.u4[h * 2 + 1] = cvtpk2bf(p2, p3);
        }
        pf[u][c] = cv.s8;
      }

#pragma unroll
    for (int u = 0; u < 2; ++u) {
      lsum[u] = __builtin_amdgcn_mfma_f32_16x16x32_bf16(pf[u][0], vone, lsum[u], 0, 0, 0);
      lsum[u] = __builtin_amdgcn_mfma_f32_16x16x32_bf16(pf[u][1], vone, lsum[u], 0, 0, 0);
    }
#pragma unroll
    for (int dt = 0; dt < 4; ++dt) {
      const int drow = (dt * 16 + l16) * 64;
#pragma unroll
      for (int c = 0; c < 2; ++c) {
        // permuted VT: the whole k-order fragment is one swizzled 16B chunk
        s16x8 vf = *(const s16x8*)&Vc[drow + (((c * 4 + quad) ^ a7) << 3)];
#pragma unroll
        for (int u = 0; u < 2; ++u)
          accO[u][dt] = __builtin_amdgcn_mfma_f32_16x16x32_bf16(pf[u][c], vf, accO[u][dt], 0, 0, 0);
      }
    }
    cur ^= 1;
  }

  short* AOb = AO + (size_t)b * LL * DD + (size_t)(bh & 15) * DHD;
#pragma unroll
  for (int u = 0; u < 2; ++u) {
    f32x4 rl;
#pragma unroll
    for (int i = 0; i < 4; ++i) rl[i] = __builtin_amdgcn_rcpf(lsum[u][i]);
#pragma unroll
    for (int dt = 0; dt < 4; ++dt)
#pragma unroll
      for (int i = 0; i < 4; ++i) {
        int qr = q0 + wv * 32 + u * 16 + quad * 4 + i;
        AOb[(size_t)qr * DD + dt * 16 + l16] = f2bf(accO[u][dt][i] * rl[i]);
      }
  }
}

extern "C" void kernel_launch(void* const* d_in, const int* in_sizes, int n_in,
                              void* d_out, int out_size, void* d_ws, size_t ws_size,
                              hipStream_t stream) {
  const float* q   = (const float*)d_in[0];
  const float* k   = (const float*)d_in[1];
  const float* v   = (const float*)d_in[2];
  const int*  mask = (const int*)d_in[3];
  const float* Wq  = (const float*)d_in[4];
  const float* Wk  = (const float*)d_in[5];
  const float* Wv  = (const float*)d_in[6];
  const float* Wo  = (const float*)d_in[7];

  const size_t SX = (size_t)BB * LL * DD;  // 8,388,608
  const size_t SW = (size_t)DD * DD;       // 1,048,576
  short* w = (short*)d_ws;
  short* qb  = w;        short* kb  = qb + SX;  short* vb  = kb + SX;
  short* Wqb = vb + SX;  short* Wkb = Wqb + SW; short* Wvb = Wkb + SW; short* Wob = Wvb + SW;
  short* Qh  = Wob + SW; short* Kh  = Qh + SX;  short* VT  = Kh + SX;
  float* maskadd = (float*)(VT + SX);
  short* AO = qb;  // qb dead after QKV projections

  prep_kernel<<<28680, 256, 0, stream>>>(q, k, v, Wq, Wk, Wv, Wo, mask,
                                         qb, kb, vb, Wqb, Wkb, Wvb, Wob, maskadd);
  qkv_gemm<<<dim3(8, 64, 3), 256, 0, stream>>>(qb, kb, vb, Wqb, Wkb, Wvb, Qh, Kh, VT);
  attn_kernel<<<dim3(LL / 128, BB * HH), 256, 0, stream>>>(Qh, Kh, VT, maskadd, AO);
  out_gemm<<<dim3(8, 64), 256, 0, stream>>>(AO, Wob, (float*)d_out);
}

// Round 7
// 308.728 us; speedup vs baseline: 1.5826x; 1.0106x over previous
//
#include <hip/hip_runtime.h>
#include <cstddef>
#include <cstdint>

#define BB 4
#define LL 2048
#define DD 1024
#define HH 16
#define DHD 64
#define QSCALE 0.18033688f  // 0.125 * log2(e): softmax in base-2 domain

typedef short s16x8 __attribute__((ext_vector_type(8)));
typedef short s16x4 __attribute__((ext_vector_type(4)));
typedef float f32x4 __attribute__((ext_vector_type(4)));
typedef unsigned int u32;
typedef u32 u32x2 __attribute__((ext_vector_type(2)));
typedef u32 u32x4 __attribute__((ext_vector_type(4)));

__device__ __forceinline__ short f2bf(float f) {
  union { float f; u32 u; } x; x.f = f;
  u32 r = x.u + 0x7FFFu + ((x.u >> 16) & 1u);
  return (short)(r >> 16);
}
// pack two f32 -> two bf16 (round-half-up) in one v_perm
__device__ __forceinline__ u32 pack2bf(float a, float b) {
  union { float f; u32 u; } x, y; x.f = a; y.f = b;
  return __builtin_amdgcn_perm(y.u + 0x8000u, x.u + 0x8000u, 0x07060302u);
}
// hardware packed f32x2 -> bf16x2 (RNE); no builtin on gfx950, asm per T12
__device__ __forceinline__ u32 cvtpk2bf(float lo, float hi) {
  u32 r;
  asm("v_cvt_pk_bf16_f32 %0, %1, %2" : "=v"(r) : "v"(lo), "v"(hi));
  return r;
}
__device__ __forceinline__ void gl2lds16(const short* g, short* l) {
  __builtin_amdgcn_global_load_lds(
      (const __attribute__((address_space(1))) unsigned int*)g,
      (__attribute__((address_space(3))) unsigned int*)l, 16, 0, 0);
}

// ---------------- merged prep: casts + mask (one launch instead of three) ----
__global__ __launch_bounds__(256) void prep_kernel(const float* __restrict__ q,
                                                   const float* __restrict__ k,
                                                   const float* __restrict__ v,
                                                   const float* __restrict__ Wq,
                                                   const float* __restrict__ Wk,
                                                   const float* __restrict__ Wv,
                                                   const float* __restrict__ Wo,
                                                   const int* __restrict__ mask,
                                                   short* __restrict__ qb,
                                                   short* __restrict__ kb,
                                                   short* __restrict__ vb,
                                                   short* __restrict__ Wqb,
                                                   short* __restrict__ Wkb,
                                                   short* __restrict__ Wvb,
                                                   short* __restrict__ Wob,
                                                   float* __restrict__ maskadd) {
  const int bb = blockIdx.x;
  if (bb < 24576) {
    const float* s; short* d;
    const int y = bb >> 13;
    if (y == 0) { s = q; d = qb; }
    else if (y == 1) { s = k; d = kb; }
    else { s = v; d = vb; }
    int i = (bb & 8191) * 256 + threadIdx.x;
    float4 x = ((const float4*)s)[i];
    s16x4 o; o.x = f2bf(x.x); o.y = f2bf(x.y); o.z = f2bf(x.z); o.w = f2bf(x.w);
    ((s16x4*)d)[i] = o;
  } else if (bb < 28672) {
    const int y = (bb - 24576) >> 10;
    const float* s; short* d; float sc = 1.0f;
    if (y == 0) { s = Wq; d = Wqb; sc = QSCALE; }
    else if (y == 1) { s = Wk; d = Wkb; }
    else if (y == 2) { s = Wv; d = Wvb; }
    else { s = Wo; d = Wob; }
    int i = ((bb - 24576) & 1023) * 256 + threadIdx.x;
    float4 x = ((const float4*)s)[i];
    s16x4 o; o.x = f2bf(x.x * sc); o.y = f2bf(x.y * sc); o.z = f2bf(x.z * sc); o.w = f2bf(x.w * sc);
    ((s16x4*)d)[i] = o;
  } else {
    int i = (bb - 28672) * 256 + threadIdx.x;
    int4 m = ((const int4*)mask)[i];
    f32x4 o;
    o[0] = (m.x == 1) ? 0.0f : -30000.0f;
    o[1] = (m.y == 1) ? 0.0f : -30000.0f;
    o[2] = (m.z == 1) ? 0.0f : -30000.0f;
    o[3] = (m.w == 1) ? 0.0f : -30000.0f;
    ((f32x4*)maskadd)[i] = o;
  }
}

// ---------------- shared GEMM core (128x128 tile, bt layout) ----------------
// Round-7: BK=32 single-barrier issue-early double-buffer (the transform
// verified in attn rounds 1/3/4). LDS stays 32 KB (2 x 128x32 per operand) ->
// 4 blocks/CU. With 64B rows the fragment read row*64B + quad*16B tiles all 32
// banks disjointly (8 bank-quads x 8 lanes = minimum phases): conflict-free
// with a LINEAR layout — no swizzle needed. A and B use the same lane->k-chunk
// mapping (quad), so the k-order is consistent and the dot product exact.
__device__ __forceinline__ void gemm_core(const short* __restrict__ A, const short* __restrict__ B,
                                          int K, int bm, int bn, short* As, short* Bs,
                                          f32x4 (&acc)[4][4]) {
  const int tid = threadIdx.x;
  const int lane = tid & 63, wave = tid >> 6;
  const int wv = __builtin_amdgcn_readfirstlane(wave);
  const int quad = lane >> 4, l16 = lane & 15;
  const int wm = (wave >> 1) * 64, wn = (wave & 1) * 64;
  const short* ap[2]; const short* bp[2]; int lofs[2];
#pragma unroll
  for (int i = 0; i < 2; ++i) {
    int s = wv * 128 + i * 64 + lane;   // 16B-chunk index in [0,512)
    int r = s >> 2, c = s & 3;          // row, k-chunk (linear)
    ap[i] = A + (size_t)(bm + r) * K + c * 8;
    bp[i] = B + (size_t)(bn + r) * K + c * 8;
    lofs[i] = s * 8;                    // shorts offset in buffer
  }
  const int rd = quad << 3;             // fragment k-chunk (linear, conflict-free)

  // prologue: stage k-step 0 into buffer 0
#pragma unroll
  for (int i = 0; i < 2; ++i) gl2lds16(ap[i], &As[lofs[i]]);
#pragma unroll
  for (int i = 0; i < 2; ++i) gl2lds16(bp[i], &Bs[lofs[i]]);

  int cur = 0;
  for (int kk = 0; kk < K; kk += 32) {
    __syncthreads();  // drains stage of step kk (vmcnt) + releases buf^1 (lgkm)
    if (kk + 32 < K) {  // issue-early: next step's loads fly under this compute
      const int nb = (cur ^ 1) * (128 * 32);
#pragma unroll
      for (int i = 0; i < 2; ++i) gl2lds16(ap[i] + kk + 32, &As[nb + lofs[i]]);
#pragma unroll
      for (int i = 0; i < 2; ++i) gl2lds16(bp[i] + kk + 32, &Bs[nb + lofs[i]]);
    }
    const short* Ac = &As[cur * (128 * 32)];
    const short* Bc = &Bs[cur * (128 * 32)];
    s16x8 af[4], bf[4];
#pragma unroll
    for (int t = 0; t < 4; ++t) af[t] = *(const s16x8*)&Ac[(wm + t * 16 + l16) * 32 + rd];
#pragma unroll
    for (int t = 0; t < 4; ++t) bf[t] = *(const s16x8*)&Bc[(wn + t * 16 + l16) * 32 + rd];
    __builtin_amdgcn_s_setprio(1);
#pragma unroll
    for (int mt = 0; mt < 4; ++mt)
#pragma unroll
      for (int nt = 0; nt < 4; ++nt)
        acc[mt][nt] = __builtin_amdgcn_mfma_f32_16x16x32_bf16(af[mt], bf[nt], acc[mt][nt], 0, 0, 0);
    __builtin_amdgcn_s_setprio(0);
    cur ^= 1;
  }
}

// fused QKV projections; grid (8, 64, 3). z=0: Q, z=1: K (head-split out), z=2: V^T out.
__global__ __launch_bounds__(256) void qkv_gemm(const short* __restrict__ qb, const short* __restrict__ kb,
                                                const short* __restrict__ vb, const short* __restrict__ Wqb,
                                                const short* __restrict__ Wkb, const short* __restrict__ Wvb,
                                                short* __restrict__ Qh, short* __restrict__ Kh,
                                                short* __restrict__ VT) {
  __shared__ short As[2 * 128 * 32];
  __shared__ short Bs[2 * 128 * 32];
  const int bid = blockIdx.x + ((blockIdx.y + (blockIdx.z << 6)) << 3);
  const int swz = (bid & 7) * 192 + (bid >> 3);
  const int bx = swz & 7, by = (swz >> 3) & 63, z = swz >> 9;
  const short *A, *B; short* C;
  if (z == 0) { A = qb; B = Wqb; C = Qh; }
  else if (z == 1) { A = kb; B = Wkb; C = Kh; }
  else { A = Wvb; B = vb; C = VT; }
  const int bm = (z == 2 ? bx : by) * 128;
  const int bn = (z == 2 ? by : bx) * 128;
  f32x4 acc[4][4] = {};
  gemm_core(A, B, DD, bm, bn, As, Bs, acc);

  const int lane = threadIdx.x & 63, wave = threadIdx.x >> 6;
  const int quad = lane >> 4, l16 = lane & 15;
  const int wm = (wave >> 1) * 64, wn = (wave & 1) * 64;
#pragma unroll
  for (int mt = 0; mt < 4; ++mt)
#pragma unroll
    for (int nt = 0; nt < 4; ++nt)
#pragma unroll
      for (int i = 0; i < 4; ++i) {
        int m = bm + wm + mt * 16 + quad * 4 + i;
        int n = bn + wn + nt * 16 + l16;
        float val = acc[mt][nt][i];
        if (z < 2) {  // head-split [B,H,L,DH]
          int b = m >> 11, l = m & 2047;
          C[((size_t)(b * HH + (n >> 6)) << 17) + (size_t)l * DHD + (n & 63)] = f2bf(val);
        } else {      // V^T [B,H,DH,L], s-permuted within each 64-token group:
          // storage pos p = {s5,s3,s2,s4,s1,s0} so attn's PV k-order fragment
          // is one contiguous 16B chunk (single swizzled ds_read_b128).
          int b = n >> 11, l = n & 2047;
          int loc = l & 63;
          int p = (loc & 0x23) | ((loc & 0x0C) << 1) | ((loc & 0x10) >> 2);
          C[((size_t)(b * DD + m) << 11) + (l & ~63) + p] = f2bf(val);
        }
      }
}

// output projection: fp32 out, grid (8, 64). nwg=512, cpx=64.
__global__ __launch_bounds__(256) void out_gemm(const short* __restrict__ A, const short* __restrict__ B,
                                                float* __restrict__ C) {
  __shared__ short As[2 * 128 * 32];
  __shared__ short Bs[2 * 128 * 32];
  const int bid = blockIdx.x + (blockIdx.y << 3);
  const int swz = (bid & 7) * 64 + (bid >> 3);
  const int bx = swz & 7, by = swz >> 3;
  const int bm = by * 128, bn = bx * 128;
  f32x4 acc[4][4] = {};
  gemm_core(A, B, DD, bm, bn, As, Bs, acc);
  const int lane = threadIdx.x & 63, wave = threadIdx.x >> 6;
  const int quad = lane >> 4, l16 = lane & 15;
  const int wm = (wave >> 1) * 64, wn = (wave & 1) * 64;
#pragma unroll
  for (int mt = 0; mt < 4; ++mt)
#pragma unroll
    for (int nt = 0; nt < 4; ++nt)
#pragma unroll
      for (int i = 0; i < 4; ++i) {
        int m = bm + wm + mt * 16 + quad * 4 + i;
        int n = bn + wn + nt * 16 + l16;
        C[(size_t)m * DD + n] = acc[mt][nt][i];
      }
}

// ---------------- flash attention, S^T formulation, max-free base-2 softmax ----
// ROUND-4 VERIFIED VERSION, byte-for-byte (77.4 us, passed, 0 bank conflicts).
// The round-5/6 2-stage pipeline failed correctness for reasons not yet
// understood; reverted per methodology (don't ship unexplained structures).
__global__ __launch_bounds__(256, 4) void attn_kernel(const short* __restrict__ Qh,
                                                      const short* __restrict__ Kh,
                                                      const short* __restrict__ VT,
                                                      const float* __restrict__ maskadd,
                                                      short* __restrict__ AO) {
  __shared__ short Ks[2][64 * 64];
  __shared__ short Vs[2][64 * 64];
  const int tid  = threadIdx.x;
  const int lane = tid & 63, wave = tid >> 6;
  const int wv   = __builtin_amdgcn_readfirstlane(wave);
  const int quad = lane >> 4, l16 = lane & 15;
  const int a7 = l16 & 7;

  // XCD-aware swizzle: nwg=1024, cpx=128 -> one XCD serves 8 heads (4 MB K/V).
  const int bid = blockIdx.x + (blockIdx.y << 4);
  const int swz = (bid & 7) * 128 + (bid >> 3);
  const int bx = swz & 15, bh = swz >> 4;
  const int b = bh >> 4;
  const int q0 = bx * 128;

  const float* mrow = maskadd + b * LL;
  const short* Qb = Qh + (size_t)bh * LL * DHD;
  const short* Kb = Kh + (size_t)bh * LL * DHD;
  const short* Vb = VT + (size_t)bh * DHD * LL;

  s16x8 qf[2][2];
#pragma unroll
  for (int u = 0; u < 2; ++u)
#pragma unroll
    for (int c = 0; c < 2; ++c)
      qf[u][c] = *(const s16x8*)&Qb[(size_t)(q0 + wv * 32 + u * 16 + l16) * DHD + c * 32 + quad * 8];

  const short* kp[2]; const short* vp[2]; int off[2];
#pragma unroll
  for (int t = 0; t < 2; ++t) {
    int s = wv * 128 + t * 64 + lane;
    int r = s >> 3, gl = (s & 7) ^ (r & 7);
    kp[t] = Kb + (size_t)r * DHD + gl * 8;
    vp[t] = Vb + (size_t)r * LL + gl * 8;
    off[t] = (wv * 128 + t * 64) * 8;
  }
  const int sw0 = (quad ^ a7) * 8;
  const int sw1 = ((4 + quad) ^ a7) * 8;

  s16x8 vone;
#pragma unroll
  for (int j = 0; j < 8; ++j) vone[j] = (short)0x3F80;  // bf16 1.0

  f32x4 lsum[2] = {};
  f32x4 accO[2][4] = {};

  // prologue: stage tile 0 into buffer 0
#pragma unroll
  for (int t = 0; t < 2; ++t) gl2lds16(kp[t], &Ks[0][off[t]]);
#pragma unroll
  for (int t = 0; t < 2; ++t) gl2lds16(vp[t], &Vs[0][off[t]]);

  int cur = 0;
  for (int s0 = 0; s0 < LL; s0 += 64) {
    __syncthreads();  // drains staging of tile t + releases buf^1
    if (s0 + 64 < LL) {  // issue-early: tile t+1 loads fly under tile t's compute
#pragma unroll
      for (int t = 0; t < 2; ++t) gl2lds16(kp[t] + (size_t)(s0 + 64) * DHD, &Ks[cur ^ 1][off[t]]);
#pragma unroll
      for (int t = 0; t < 2; ++t) gl2lds16(vp[t] + (s0 + 64), &Vs[cur ^ 1][off[t]]);
    }
    f32x4 mm[4];
#pragma unroll
    for (int st = 0; st < 4; ++st) mm[st] = *(const f32x4*)&mrow[s0 + st * 16 + quad * 4];

    const short* Kc = Ks[cur];
    const short* Vc = Vs[cur];
    s16x8 kf[4][2];
#pragma unroll
    for (int st = 0; st < 4; ++st) {
      kf[st][0] = *(const s16x8*)&Kc[(st * 16 + l16) * 64 + sw0];
      kf[st][1] = *(const s16x8*)&Kc[(st * 16 + l16) * 64 + sw1];
    }
    f32x4 sc[2][4];
#pragma unroll
    for (int u = 0; u < 2; ++u)
#pragma unroll
      for (int st = 0; st < 4; ++st) {
        sc[u][st] = __builtin_amdgcn_mfma_f32_16x16x32_bf16(kf[st][0], qf[u][0], mm[st], 0, 0, 0);
        sc[u][st] = __builtin_amdgcn_mfma_f32_16x16x32_bf16(kf[st][1], qf[u][1], sc[u][st], 0, 0, 0);
      }

    // P = exp2(score), packed straight into the PV A-fragment (permuted k-order)
    s16x8 pf[2][2];
#pragma unroll
    for (int u = 0; u < 2; ++u)
#pragma unroll
      for (int c = 0; c < 2; ++c) {
        union { u32x4 u4; s16x8 s8; } cv;
#pragma unroll
        for (int h = 0; h < 2; ++h) {
          const int st = 2 * c + h;
          float p0 = __builtin_amdgcn_exp2f(sc[u][st][0]);
          float p1 = __builtin_amdgcn_exp2f(sc[u][st][1]);
          float p2 = __builtin_amdgcn_exp2f(sc[u][st][2]);
          float p3 = __builtin_amdgcn_exp2f(sc[u][st][3]);
          cv.u4[h * 2 + 0] = cvtpk2bf(p0, p1);
          cv.u4[h * 2 + 1] = cvtpk2bf(p2, p3);
        }
        pf[u][c] = cv.s8;
      }

#pragma unroll
    for (int u = 0; u < 2; ++u) {
      lsum[u] = __builtin_amdgcn_mfma_f32_16x16x32_bf16(pf[u][0], vone, lsum[u], 0, 0, 0);
      lsum[u] = __builtin_amdgcn_mfma_f32_16x16x32_bf16(pf[u][1], vone, lsum[u], 0, 0, 0);
    }
#pragma unroll
    for (int dt = 0; dt < 4; ++dt) {
      const int drow = (dt * 16 + l16) * 64;
#pragma unroll
      for (int c = 0; c < 2; ++c) {
        // permuted VT: the whole k-order fragment is one swizzled 16B chunk
        s16x8 vf = *(const s16x8*)&Vc[drow + (((c * 4 + quad) ^ a7) << 3)];
#pragma unroll
        for (int u = 0; u < 2; ++u)
          accO[u][dt] = __builtin_amdgcn_mfma_f32_16x16x32_bf16(pf[u][c], vf, accO[u][dt], 0, 0, 0);
      }
    }
    cur ^= 1;
  }

  short* AOb = AO + (size_t)b * LL * DD + (size_t)(bh & 15) * DHD;
#pragma unroll
  for (int u = 0; u < 2; ++u) {
    f32x4 rl;
#pragma unroll
    for (int i = 0; i < 4; ++i) rl[i] = __builtin_amdgcn_rcpf(lsum[u][i]);
#pragma unroll
    for (int dt = 0; dt < 4; ++dt)
#pragma unroll
      for (int i = 0; i < 4; ++i) {
        int qr = q0 + wv * 32 + u * 16 + quad * 4 + i;
        AOb[(size_t)qr * DD + dt * 16 + l16] = f2bf(accO[u][dt][i] * rl[i]);
      }
  }
}

extern "C" void kernel_launch(void* const* d_in, const int* in_sizes, int n_in,
                              void* d_out, int out_size, void* d_ws, size_t ws_size,
                              hipStream_t stream) {
  const float* q   = (const float*)d_in[0];
  const float* k   = (const float*)d_in[1];
  const float* v   = (const float*)d_in[2];
  const int*  mask = (const int*)d_in[3];
  const float* Wq  = (const float*)d_in[4];
  const float* Wk  = (const float*)d_in[5];
  const float* Wv  = (const float*)d_in[6];
  const float* Wo  = (const float*)d_in[7];

  const size_t SX = (size_t)BB * LL * DD;  // 8,388,608
  const size_t SW = (size_t)DD * DD;       // 1,048,576
  short* w = (short*)d_ws;
  short* qb  = w;        short* kb  = qb + SX;  short* vb  = kb + SX;
  short* Wqb = vb + SX;  short* Wkb = Wqb + SW; short* Wvb = Wkb + SW; short* Wob = Wvb + SW;
  short* Qh  = Wob + SW; short* Kh  = Qh + SX;  short* VT  = Kh + SX;
  float* maskadd = (float*)(VT + SX);
  short* AO = qb;  // qb dead after QKV projections

  prep_kernel<<<28680, 256, 0, stream>>>(q, k, v, Wq, Wk, Wv, Wo, mask,
                                         qb, kb, vb, Wqb, Wkb, Wvb, Wob, maskadd);
  qkv_gemm<<<dim3(8, 64, 3), 256, 0, stream>>>(qb, kb, vb, Wqb, Wkb, Wvb, Qh, Kh, VT);
  attn_kernel<<<dim3(LL / 128, BB * HH), 256, 0, stream>>>(Qh, Kh, VT, maskadd, AO);
  out_gemm<<<dim3(8, 64), 256, 0, stream>>>(AO, Wob, (float*)d_out);
}